// Round 11
// baseline (193.799 us; speedup 1.0000x reference)
//
#include <hip/hip_runtime.h>

// Problem constants
#define S_DIM 8192
#define K_DIM 1024
#define RO_DIM 4096
#define O_DIM 64
#define SO (S_DIM * O_DIM)

typedef __attribute__((ext_vector_type(8))) __bf16 bf16x8;
typedef __attribute__((ext_vector_type(4))) float floatx4;
typedef __attribute__((ext_vector_type(4))) unsigned short ushx4;
typedef __attribute__((ext_vector_type(8))) unsigned short ushx8;

__device__ inline unsigned short f2bf(float f) {
  unsigned u = __builtin_bit_cast(unsigned, f);
  u += 0x7fff + ((u >> 16) & 1);  // round-to-nearest-even
  return (unsigned short)(u >> 16);
}
__device__ inline float bf2f(unsigned short h) {
  unsigned u = ((unsigned)h) << 16;
  return __builtin_bit_cast(float, u);
}

// ---------------------------------------------------------------- cast
// X -> Xb row-major bf16 (for global_load_lds A staging).
// W -> Wt fragment-major bf16: chunk c = n16*2048 + kc*16 + nl holds
// W[n16*16+nl][kc*8 .. kc*8+7]; a wave's B-fragment load is 1 KB contiguous.
__global__ __launch_bounds__(256) void cast_kernel(const float* __restrict__ X,
                                                   const float* __restrict__ W,
                                                   unsigned short* __restrict__ Xb,
                                                   unsigned short* __restrict__ Wt) {
  int b = blockIdx.x;
  if (b < 2048) {  // X: 2,097,152 float4 groups, 4 per thread
#pragma unroll
    for (int i = 0; i < 4; ++i) {
      int g = b * 1024 + i * 256 + threadIdx.x;
      float4 v = ((const float4*)X)[g];
      ushx4 o;
      o.x = f2bf(v.x); o.y = f2bf(v.y); o.z = f2bf(v.z); o.w = f2bf(v.w);
      *(ushx4*)(Xb + (size_t)g * 4) = o;
    }
  } else {  // W: 524,288 8-elem chunks, 4 per thread; coalesced writes
    int wb = b - 2048;  // 0..511
#pragma unroll
    for (int i = 0; i < 4; ++i) {
      int c = wb * 1024 + i * 256 + threadIdx.x;
      int n16 = c >> 11;
      int r = c & 2047;
      int kc = r >> 4;
      int nl = r & 15;
      const float* src = W + (size_t)(n16 * 16 + nl) * K_DIM + kc * 8;
      float4 v0 = *(const float4*)src;
      float4 v1 = *(const float4*)(src + 4);
      ushx8 o;
      o[0] = f2bf(v0.x); o[1] = f2bf(v0.y); o[2] = f2bf(v0.z); o[3] = f2bf(v0.w);
      o[4] = f2bf(v1.x); o[5] = f2bf(v1.y); o[6] = f2bf(v1.z); o[7] = f2bf(v1.w);
      *(ushx8*)(Wt + (size_t)c * 8) = o;
    }
  }
}

// ---- A-tile staging: 128 rows x 64 k into dst, K-chunk XOR swizzle (row&7)
// applied at the GLOBAL address (LDS dest stays wave-uniform + lane*16).
__device__ __forceinline__ void stage_A(const unsigned short* __restrict__ Xb,
                                        unsigned short* dst, int gm0, int k0, int t) {
#pragma unroll
  for (int i = 0; i < 4; ++i) {
    int idx = i * 256 + t;       // 0..1023, lane-contiguous within each wave
    int row = idx >> 3;          // tile row 0..127
    int cc = idx & 7;            // LDS chunk slot within BK=64
    int gcc = cc ^ (row & 7);    // global k-chunk held in this slot
    const unsigned short* ga = Xb + (size_t)(gm0 + row) * K_DIM + k0 + gcc * 8;
    __builtin_amdgcn_global_load_lds(
        (const __attribute__((address_space(1))) void*)ga,
        (__attribute__((address_space(3))) void*)(dst + idx * 8), 16, 0, 0);
  }
}

// ---- one 64-k compute step: 8 streamed B-fragments + 8 A ds_read_b128 + 16 MFMA
__device__ __forceinline__ void compute64(const unsigned short* __restrict__ Wt,
                                          const unsigned short* At,
                                          floatx4 (&acc)[4][2][2],
                                          int n16base, int k0,
                                          int wm, int oh, int quad, int l16) {
  bf16x8 bfr[2][2][2];  // [s][rh][ni]
#pragma unroll
  for (int s = 0; s < 2; ++s)
#pragma unroll
    for (int rh = 0; rh < 2; ++rh)
#pragma unroll
      for (int ni = 0; ni < 2; ++ni) {
        int n16 = n16base + rh * 4 + oh * 2 + ni;
        int kc = (k0 >> 3) + s * 4 + quad;
        bfr[s][rh][ni] = *(const bf16x8*)(Wt + (((size_t)n16 * 128 + kc) * 16 + l16) * 8);
      }
#pragma unroll
  for (int s = 0; s < 2; ++s) {
    bf16x8 af[4];
#pragma unroll
    for (int mi = 0; mi < 4; ++mi) {
      int row = wm * 64 + mi * 16 + l16;
      int cc = (s * 4 + quad) ^ (row & 7);
      af[mi] = *(const bf16x8*)(At + row * 64 + cc * 8);
    }
#pragma unroll
    for (int mi = 0; mi < 4; ++mi)
#pragma unroll
      for (int rh = 0; rh < 2; ++rh)
#pragma unroll
        for (int ni = 0; ni < 2; ++ni)
          acc[mi][rh][ni] = __builtin_amdgcn_mfma_f32_16x16x32_bf16(
              af[mi], bfr[s][rh][ni], acc[mi][rh][ni], 0, 0, 0);
  }
}

// ---------------------------------------------------------------- fused GEMM+sigmoid+rule-reduce
// R9 frame (128x128, BK=64, 4 waves x 16x16x32, B streamed from Wt, 0 confl)
// + 2-stage A double-buffer with ONE barrier per 64-k step:
//   barrier -> issue DMA(tile k+1, other buf) -> compute(tile k).
// R9 exposed the A-DMA latency behind its second barrier every iteration
// (issue DMA -> bfr loads -> barrier drains vmcnt(0) -> compute) with only
// ~1.6 waves/SIMD to hide it — the measured ~28% all-pipe idle. Now the DMA
// has a full compute phase in flight to hide under, and barriers halve 32->16.
// Enabled by R9's B-streaming: A is the only LDS client (2x16KB + 1KB lamsh).
// - Bias folded into acc init (exact); lambda via 1KB LDS side-buffer.
// - NO min-waves bound (R2: spill). NO rule-loop (R7: +194MB fetch).
//   NO threadfence ticket (R8). NO M=256/512-thread block (R10: post-timing
//   divergence + occupancy loss — reverted wholesale).
// - fp8/MX rejected on numerics (threshold 0.46, bf16 absmax already 0.125).
__global__ __launch_bounds__(256) void gemm_kernel(const unsigned short* __restrict__ Xb,
                                                   const unsigned short* __restrict__ Wt,
                                                   const float* __restrict__ bias,
                                                   const float* __restrict__ lam,
                                                   unsigned short* __restrict__ partial) {
  __shared__ __align__(16) unsigned char smem[33792];
  unsigned short* At0 = (unsigned short*)smem;             // 16 KB
  unsigned short* At1 = (unsigned short*)(smem + 16384);   // 16 KB
  float* lamsh = (float*)(smem + 32768);                   // [128][2] (1 KB)

  const int t = threadIdx.x;
  const int lane = t & 63;
  const int w = t >> 6;
  const int wm = w & 1;        // wave row half (rows wm*64..+63)
  const int oh = w >> 1;       // o-column half (cols oh*32..+31 of each rule)
  const int quad = lane >> 4;  // 0..3
  const int l16 = lane & 15;
  const int gm0 = blockIdx.y * 128;
  const int gn0 = blockIdx.x * 128;
  const int n16base = blockIdx.x * 8;  // gn0/16

  // stage lambda interleaved: lamsh[row*2+rl] = lam[gm0+row, bx*2+rl]
  {
    int row = t >> 1, rl = t & 1;
    lamsh[t] = lam[(size_t)(gm0 + row) * 64 + blockIdx.x * 2 + rl];
  }

  // acc init = bias (C/D col = l16, same for all 4 regs) — exact fold
  floatx4 acc[4][2][2];
#pragma unroll
  for (int rh = 0; rh < 2; ++rh)
#pragma unroll
    for (int ni = 0; ni < 2; ++ni) {
      float bv = bias[gn0 + rh * 64 + oh * 32 + ni * 16 + l16];
#pragma unroll
      for (int mi = 0; mi < 4; ++mi)
        acc[mi][rh][ni] = (floatx4){bv, bv, bv, bv};
    }

  // ---- 2-stage pipelined K-loop (x2 unroll for static buffer parity) ----
  stage_A(Xb, At0, gm0, 0, t);
  for (int k0 = 0; k0 < K_DIM; k0 += 128) {
    __syncthreads();                       // At0 DMA done; old At0 readers done
    stage_A(Xb, At1, gm0, k0 + 64, t);     // always valid (k0+64 <= 960)
    compute64(Wt, At0, acc, n16base, k0, wm, oh, quad, l16);
    __syncthreads();                       // At1 DMA done; old At1 readers done
    if (k0 + 128 < K_DIM) stage_A(Xb, At0, gm0, k0 + 128, t);
    compute64(Wt, At1, acc, n16base, k0 + 64, wm, oh, quad, l16);
  }

  // ---- epilogue: pure-register rule-sum, direct bf16 slice store ----
  unsigned short* pbase = partial + (size_t)blockIdx.x * SO + (size_t)gm0 * O_DIM;
#pragma unroll
  for (int mi = 0; mi < 4; ++mi) {
#pragma unroll
    for (int reg = 0; reg < 4; ++reg) {
      int row = wm * 64 + mi * 16 + quad * 4 + reg;
      float2 lv = *(const float2*)(lamsh + row * 2);
#pragma unroll
      for (int ni = 0; ni < 2; ++ni) {
        float h0 = 1.f / (1.f + __expf(-acc[mi][0][ni][reg]));
        float h1 = 1.f / (1.f + __expf(-acc[mi][1][ni][reg]));
        float y = lv.x * h0 + lv.y * h1;
        pbase[(size_t)row * O_DIM + oh * 32 + ni * 16 + l16] = f2bf(y);
      }
    }
  }
}

// ---------------------------------------------------------------- final reduce over 32 N-tiles
__global__ __launch_bounds__(256) void reduce_kernel(const unsigned short* __restrict__ partial,
                                                     float* __restrict__ Y) {
  int i4 = blockIdx.x * 256 + threadIdx.x;  // index of a 4-elem group
  float s0 = 0.f, s1 = 0.f, s2 = 0.f, s3 = 0.f;
#pragma unroll
  for (int c = 0; c < 32; ++c) {
    ushx4 v = ((const ushx4*)(partial + (size_t)c * SO))[i4];
    s0 += bf2f(v.x); s1 += bf2f(v.y); s2 += bf2f(v.z); s3 += bf2f(v.w);
  }
  ((float4*)Y)[i4] = (float4){s0, s1, s2, s3};
}

extern "C" void kernel_launch(void* const* d_in, const int* in_sizes, int n_in,
                              void* d_out, int out_size, void* d_ws, size_t ws_size,
                              hipStream_t stream) {
  const float* X = (const float*)d_in[0];     // [8192,1024]
  const float* W = (const float*)d_in[1];     // [4096,1024]
  const float* b = (const float*)d_in[2];     // [4096]
  const float* lam = (const float*)d_in[3];   // [8192,64]
  float* Y = (float*)d_out;                   // [8192,64]

  unsigned short* Xb = (unsigned short*)d_ws;                       // 16 MB
  unsigned short* Wt = Xb + (size_t)S_DIM * K_DIM;                  // 8 MB (fragment layout)
  unsigned short* partial = Wt + (size_t)RO_DIM * K_DIM;            // 32 slices x 1 MB = 32 MB

  cast_kernel<<<2560, 256, 0, stream>>>(X, W, Xb, Wt);

  dim3 g(RO_DIM / 128, S_DIM / 128);  // (32, 64)
  gemm_kernel<<<g, 256, 0, stream>>>(Xb, Wt, b, lam, partial);

  reduce_kernel<<<SO / 1024, 256, 0, stream>>>(partial, Y);
}